// Round 1
// baseline (3383.185 us; speedup 1.0000x reference)
//
#include <hip/hip_runtime.h>
#include <stdint.h>

#define N_TOK 4096
#define DS 2048
#define DB 5120
#define ISDM 13824
#define TOPK 128

typedef short bf16x8 __attribute__((ext_vector_type(8)));
typedef float f32x4 __attribute__((ext_vector_type(4)));

__device__ __forceinline__ ushort f2b(float f) {
  uint32_t u = __float_as_uint(f);
  u = (u + 0x7fff + ((u >> 16) & 1)) >> 16;
  return (ushort)u;
}
__device__ __forceinline__ float bl(uint32_t u) { return __uint_as_float(u << 16); }
__device__ __forceinline__ float bh(uint32_t u) { return __uint_as_float(u & 0xffff0000u); }

__device__ __forceinline__ float dot8(uint4 a, uint4 b) {
  return bl(a.x)*bl(b.x) + bh(a.x)*bh(b.x)
       + bl(a.y)*bl(b.y) + bh(a.y)*bh(b.y)
       + bl(a.z)*bl(b.z) + bh(a.z)*bh(b.z)
       + bl(a.w)*bl(b.w) + bh(a.w)*bh(b.w);
}
__device__ __forceinline__ void acc8(float* a, uint4 p, float g) {
  a[0] += g * bl(p.x); a[1] += g * bh(p.x);
  a[2] += g * bl(p.y); a[3] += g * bh(p.y);
  a[4] += g * bl(p.z); a[5] += g * bh(p.z);
  a[6] += g * bl(p.w); a[7] += g * bh(p.w);
}
__device__ __forceinline__ void store8(ushort* o, const float* a) {
  ushort4 u0; u0.x = f2b(a[0]); u0.y = f2b(a[1]); u0.z = f2b(a[2]); u0.w = f2b(a[3]);
  ushort4 u1; u1.x = f2b(a[4]); u1.y = f2b(a[5]); u1.z = f2b(a[6]); u1.w = f2b(a[7]);
  ((ushort4*)o)[0] = u0; ((ushort4*)o)[1] = u1;
}

// ---------------- fp32 -> bf16 convert ----------------
__global__ void k_convert(const float* __restrict__ in, ushort* __restrict__ out, int n4) {
  int i = blockIdx.x * blockDim.x + threadIdx.x;
  if (i >= n4) return;
  float4 v = ((const float4*)in)[i];
  ushort4 o; o.x = f2b(v.x); o.y = f2b(v.y); o.z = f2b(v.z); o.w = f2b(v.w);
  ((ushort4*)out)[i] = o;
}

// ---------------- transpose sdm_down [DB][ISDM] f32 -> downT [ISDM][DB] bf16 ----------------
__global__ void k_transpose(const float* __restrict__ in, ushort* __restrict__ out) {
  __shared__ float tile[32][33];
  int ix = blockIdx.x * 32 + threadIdx.x;   // ISDM dim
  int iy0 = blockIdx.y * 32;                // DB dim
  #pragma unroll
  for (int j = 0; j < 4; j++)
    tile[threadIdx.y + j*8][threadIdx.x] = in[(size_t)(iy0 + threadIdx.y + j*8) * ISDM + ix];
  __syncthreads();
  int ox = iy0 + threadIdx.x;               // DB dim (contiguous out)
  int oy0 = blockIdx.x * 32;                // ISDM dim
  #pragma unroll
  for (int j = 0; j < 4; j++)
    out[(size_t)(oy0 + threadIdx.y + j*8) * DB + ox] = f2b(tile[threadIdx.x][threadIdx.y + j*8]);
}

// ---------------- LayerNorm -> bf16 ----------------
__global__ __launch_bounds__(256) void k_ln(const float* __restrict__ h,
                                            const float* __restrict__ sc,
                                            const float* __restrict__ bi,
                                            ushort* __restrict__ xo) {
  __shared__ float red[8];
  int row = blockIdx.x, tid = threadIdx.x;
  const float* hr = h + (size_t)row * DS;
  float v[8]; float s = 0.f;
  #pragma unroll
  for (int i = 0; i < 8; i++) { v[i] = hr[tid + i*256]; s += v[i]; }
  for (int o = 32; o; o >>= 1) s += __shfl_down(s, o);
  if ((tid & 63) == 0) red[tid >> 6] = s;
  __syncthreads();
  if (tid == 0) red[4] = red[0]+red[1]+red[2]+red[3];
  __syncthreads();
  float mu = red[4] * (1.0f/DS);
  float s2 = 0.f;
  #pragma unroll
  for (int i = 0; i < 8; i++) { float d = v[i]-mu; s2 += d*d; }
  for (int o = 32; o; o >>= 1) s2 += __shfl_down(s2, o);
  __syncthreads();
  if ((tid & 63) == 0) red[tid >> 6] = s2;
  __syncthreads();
  if (tid == 0) red[5] = red[0]+red[1]+red[2]+red[3];
  __syncthreads();
  float rs = rsqrtf(red[5]*(1.0f/DS) + 1e-5f);
  ushort* xr = xo + (size_t)row * DS;
  #pragma unroll
  for (int i = 0; i < 8; i++) {
    int c = tid + i*256;
    xr[c] = f2b((v[i]-mu)*rs*sc[c] + bi[c]);
  }
}

// ---------------- bf16 MFMA gemm_bt: C[m][n] = sum_k A[m][k]*B[n][k] ----------------
// EPI 0: store bf16   EPI 1: silu -> fp32   EPI 2: fp32 out = resid + v*tanh(gs[n])
template<int EPI>
__global__ __launch_bounds__(256) void k_gemm_bt(
    const ushort* __restrict__ A, const ushort* __restrict__ B,
    void* __restrict__ outp, int M, int N, int K,
    const float* __restrict__ resid, const float* __restrict__ gs)
{
  __shared__ __align__(16) ushort As[128*40];   // stride 40: 2-way bank alias only
  __shared__ __align__(16) ushort Bs[128*40];
  const int tid = threadIdx.x;
  const int m0 = blockIdx.y * 128, n0 = blockIdx.x * 128;
  const int wave = tid >> 6, lane = tid & 63;
  const int wm = (wave >> 1) * 64, wn = (wave & 1) * 64;
  const int quad = lane >> 4, l16 = lane & 15;
  const int ar = tid >> 2, ac = (tid & 3) * 8;

  const ushort* Ap  = A + (size_t)(m0 + ar) * K + ac;
  const ushort* Ap2 = Ap + (size_t)64 * K;
  const ushort* Bp  = B + (size_t)(n0 + ar) * K + ac;
  const ushort* Bp2 = Bp + (size_t)64 * K;

  f32x4 acc[4][4];
  f32x4 zero = {0.f, 0.f, 0.f, 0.f};
  #pragma unroll
  for (int mt = 0; mt < 4; mt++)
    #pragma unroll
    for (int nt = 0; nt < 4; nt++) acc[mt][nt] = zero;

  for (int k0 = 0; k0 < K; k0 += 32) {
    uint4 a0 = *(const uint4*)(Ap  + k0);
    uint4 a1 = *(const uint4*)(Ap2 + k0);
    uint4 b0 = *(const uint4*)(Bp  + k0);
    uint4 b1 = *(const uint4*)(Bp2 + k0);
    __syncthreads();
    *(uint4*)&As[ar*40 + ac]      = a0;
    *(uint4*)&As[(ar+64)*40 + ac] = a1;
    *(uint4*)&Bs[ar*40 + ac]      = b0;
    *(uint4*)&Bs[(ar+64)*40 + ac] = b1;
    __syncthreads();
    bf16x8 af[4], bfr[4];
    #pragma unroll
    for (int mt = 0; mt < 4; mt++)
      af[mt] = *(const bf16x8*)&As[(wm + mt*16 + l16)*40 + quad*8];
    #pragma unroll
    for (int nt = 0; nt < 4; nt++)
      bfr[nt] = *(const bf16x8*)&Bs[(wn + nt*16 + l16)*40 + quad*8];
    #pragma unroll
    for (int mt = 0; mt < 4; mt++)
      #pragma unroll
      for (int nt = 0; nt < 4; nt++)
        acc[mt][nt] = __builtin_amdgcn_mfma_f32_16x16x32_bf16(af[mt], bfr[nt], acc[mt][nt], 0, 0, 0);
  }

  #pragma unroll
  for (int mt = 0; mt < 4; mt++) {
    #pragma unroll
    for (int nt = 0; nt < 4; nt++) {
      #pragma unroll
      for (int r = 0; r < 4; r++) {
        int row = m0 + wm + mt*16 + quad*4 + r;   // C/D layout: row=(lane>>4)*4+reg
        int col = n0 + wn + nt*16 + l16;          //             col=lane&15
        float v = acc[mt][nt][r];
        if (EPI == 0) {
          ((ushort*)outp)[(size_t)row * N + col] = f2b(v);
        } else if (EPI == 1) {
          ((float*)outp)[(size_t)row * N + col] = v / (1.0f + __expf(-v));
        } else {
          ((float*)outp)[(size_t)row * N + col] =
              resid[(size_t)row * N + col] + v * tanhf(gs[col]);
        }
      }
    }
  }
}

// ---------------- per-token top-K by |g|, fp32 keys, bitwise binary search ----------------
__global__ __launch_bounds__(256) void k_topk(const float* __restrict__ g,
                                              int* __restrict__ idx_out,
                                              float* __restrict__ gsel_out) {
  __shared__ uint32_t keys[ISDM];
  __shared__ int red[4];
  __shared__ int scnt, eqn;
  __shared__ int eqlist[512];
  int t = blockIdx.x, tid = threadIdx.x;
  const float* gr = g + (size_t)t * ISDM;
  for (int i = tid; i < ISDM; i += 256)
    keys[i] = __float_as_uint(gr[i]) & 0x7fffffffu;
  if (tid == 0) { scnt = 0; eqn = 0; }
  __syncthreads();

  uint32_t thr = 0;
  for (int bit = 30; bit >= 0; bit--) {
    uint32_t cand = thr | (1u << bit);
    int c = 0;
    for (int i = tid; i < ISDM; i += 256) c += (keys[i] >= cand);
    for (int o = 32; o; o >>= 1) c += __shfl_down(c, o);
    if ((tid & 63) == 0) red[tid >> 6] = c;
    __syncthreads();
    int tot = red[0] + red[1] + red[2] + red[3];
    if (tot >= TOPK) thr = cand;
    __syncthreads();
  }
  // thr = K-th largest key. Take all > thr, fill with ==thr by lowest index (jax tie-break).
  for (int i = tid; i < ISDM; i += 256) {
    uint32_t k = keys[i];
    if (k > thr) {
      int p = atomicAdd(&scnt, 1);
      idx_out[t*TOPK + p] = i;
      gsel_out[t*TOPK + p] = gr[i];
    } else if (k == thr) {
      int p = atomicAdd(&eqn, 1);
      if (p < 512) eqlist[p] = i;
    }
  }
  __syncthreads();
  if (tid == 0) {
    int need = TOPK - scnt;
    int ne = eqn < 512 ? eqn : 512;
    for (int a = 0; a < need; a++) {
      int best = a;
      for (int b = a+1; b < ne; b++) if (eqlist[b] < eqlist[best]) best = b;
      int tmp = eqlist[a]; eqlist[a] = eqlist[best]; eqlist[best] = tmp;
      int i = eqlist[a];
      idx_out[t*TOPK + scnt + a] = i;
      gsel_out[t*TOPK + scnt + a] = gr[i];
    }
  }
}

// ---------------- gu[t][k] = gsel * dot(x_big[t], up[idx[t][k]]) ----------------
__global__ __launch_bounds__(256) void k_gather_up(const ushort* __restrict__ xbig,
                                                   const ushort* __restrict__ up,
                                                   const int* __restrict__ idx,
                                                   const float* __restrict__ gsel,
                                                   float* __restrict__ gu) {
  int t = blockIdx.y;
  int k = blockIdx.x * 4 + (threadIdx.x >> 6);
  int lane = threadIdx.x & 63;
  int i = idx[t*TOPK + k];
  const uint4* xr = (const uint4*)(xbig + (size_t)t * DB);
  const uint4* ur = (const uint4*)(up + (size_t)i * DB);
  float s = 0.f;
  #pragma unroll
  for (int j = 0; j < 10; j++) {
    uint4 x4 = xr[lane + j*64];
    uint4 u4 = ur[lane + j*64];
    s += dot8(x4, u4);
  }
  for (int o = 32; o; o >>= 1) s += __shfl_down(s, o);
  if (lane == 0) gu[t*TOPK + k] = gsel[t*TOPK + k] * s;
}

// ---------------- retrieved_big[t] = sum_k gu[t][k] * downT[idx[t][k]] ----------------
__global__ __launch_bounds__(256) void k_down(const ushort* __restrict__ downT,
                                              const int* __restrict__ idx,
                                              const float* __restrict__ gu,
                                              ushort* __restrict__ rbig) {
  __shared__ int sidx[TOPK];
  __shared__ float sgu[TOPK];
  int t = blockIdx.x, tid = threadIdx.x;
  if (tid < TOPK) { sidx[tid] = idx[t*TOPK + tid]; sgu[tid] = gu[t*TOPK + tid]; }
  __syncthreads();
  float a0[8] = {0,0,0,0,0,0,0,0};
  float a1[8] = {0,0,0,0,0,0,0,0};
  int c0 = tid, c1 = tid + 256;           // 320 uint4-chunks cover 5120 bf16
  bool has2 = (c1 < 320);
  for (int k = 0; k < TOPK; k++) {
    const uint4* dr = (const uint4*)(downT + (size_t)sidx[k] * DB);
    float gk = sgu[k];
    uint4 p = dr[c0];
    acc8(a0, p, gk);
    if (has2) { uint4 q = dr[c1]; acc8(a1, q, gk); }
  }
  ushort* outr = rbig + (size_t)t * DB;
  store8(outr + c0*8, a0);
  if (has2) store8(outr + c1*8, a1);
}

extern "C" void kernel_launch(void* const* d_in, const int* in_sizes, int n_in,
                              void* d_out, int out_size, void* d_ws, size_t ws_size,
                              hipStream_t stream) {
  const float* h        = (const float*)d_in[0];
  const float* ln_scale = (const float*)d_in[1];
  const float* ln_bias  = (const float*)d_in[2];
  const float* w_in     = (const float*)d_in[3];
  const float* w_out    = (const float*)d_in[4];
  const float* gate_sm  = (const float*)d_in[5];
  const float* sdm_gate = (const float*)d_in[6];
  const float* sdm_up   = (const float*)d_in[7];
  const float* sdm_down = (const float*)d_in[8];
  float* out = (float*)d_out;

  char* w = (char*)d_ws;
  size_t off = 0;
  auto alloc = [&](size_t bytes) -> void* {
    void* p = w + off; off += (bytes + 255) & ~(size_t)255; return p;
  };
  ushort* x_b    = (ushort*)alloc((size_t)N_TOK*DS*2);
  ushort* win_b  = (ushort*)alloc((size_t)DB*DS*2);
  ushort* wout_b = (ushort*)alloc((size_t)DS*DB*2);
  ushort* gate_b = (ushort*)alloc((size_t)ISDM*DB*2);
  ushort* up_b   = (ushort*)alloc((size_t)ISDM*DB*2);
  ushort* downT  = (ushort*)alloc((size_t)ISDM*DB*2);
  ushort* xbig_b = (ushort*)alloc((size_t)N_TOK*DB*2);
  float*  gfull  = (float*)alloc((size_t)N_TOK*ISDM*4);
  int*    idx    = (int*)alloc((size_t)N_TOK*TOPK*4);
  float*  gsel   = (float*)alloc((size_t)N_TOK*TOPK*4);
  float*  gu     = (float*)alloc((size_t)N_TOK*TOPK*4);
  ushort* rbig   = (ushort*)alloc((size_t)N_TOK*DB*2);

  // weight conversions (ws is re-poisoned every call, so redo each launch)
  k_convert<<<(DB*DS/4 + 255)/256, 256, 0, stream>>>(w_in, win_b, DB*DS/4);
  k_convert<<<(DS*DB/4 + 255)/256, 256, 0, stream>>>(w_out, wout_b, DS*DB/4);
  k_convert<<<(ISDM*DB/4 + 255)/256, 256, 0, stream>>>(sdm_gate, gate_b, ISDM*DB/4);
  k_convert<<<(ISDM*DB/4 + 255)/256, 256, 0, stream>>>(sdm_up, up_b, ISDM*DB/4);
  k_transpose<<<dim3(ISDM/32, DB/32), dim3(32, 8), 0, stream>>>(sdm_down, downT);

  // LayerNorm
  k_ln<<<N_TOK, 256, 0, stream>>>(h, ln_scale, ln_bias, x_b);

  // proj_in: x_big = x @ w_in^T  [4096 x 5120], K=2048
  k_gemm_bt<0><<<dim3(DB/128, N_TOK/128), 256, 0, stream>>>(
      x_b, win_b, xbig_b, N_TOK, DB, DS, nullptr, nullptr);

  // gate: g_full = silu(x_big @ sdm_gate^T)  [4096 x 13824], K=5120
  k_gemm_bt<1><<<dim3(ISDM/128, N_TOK/128), 256, 0, stream>>>(
      xbig_b, gate_b, gfull, N_TOK, ISDM, DB, nullptr, nullptr);

  // top-k per token
  k_topk<<<N_TOK, 256, 0, stream>>>(gfull, idx, gsel);

  // u_sel gather-dot + gu
  k_gather_up<<<dim3(TOPK/4, N_TOK), 256, 0, stream>>>(xbig_b, up_b, idx, gsel, gu);

  // down gather-accumulate -> retrieved_big (bf16)
  k_down<<<N_TOK, 256, 0, stream>>>(downT, idx, gu, rbig);

  // proj_out + tanh-gated residual -> out  [4096 x 2048], K=5120
  k_gemm_bt<2><<<dim3(DS/128, N_TOK/128), 256, 0, stream>>>(
      rbig, wout_b, out, N_TOK, DS, DB, h, gate_sm);
}